// Round 9
// baseline (184.157 us; speedup 1.0000x reference)
//
#include <hip/hip_runtime.h>
#include <math.h>

#define DIM 256

// 8-byte vector with 4-byte alignment promise: legal at odd z offsets.
typedef float f2v __attribute__((ext_vector_type(2), aligned(4)));

// ---------------------------------------------------------------------------
// Setup kernel: single thread computes the 3x4 voxel->voxel transform T and
// writes 12 floats to workspace.  T = inv(flo_v2r) @ T_rig @ ref_v2r, with
// T_rig = [[Rx@Ry@Rz, t],[0,0,0,1]]  (matches the JAX reference composition).
// ---------------------------------------------------------------------------

__device__ void matmul4(const float* A, const float* B, float* C) {
    for (int r = 0; r < 4; ++r)
        for (int c = 0; c < 4; ++c) {
            float acc = 0.f;
            for (int k = 0; k < 4; ++k) acc += A[r * 4 + k] * B[k * 4 + c];
            C[r * 4 + c] = acc;
        }
}

__device__ void invert4(const float* A, float* inv) {
    // Gauss-Jordan with partial pivoting on a [4][8] augmented matrix.
    float M[4][8];
    for (int r = 0; r < 4; ++r) {
        for (int c = 0; c < 4; ++c) M[r][c] = A[r * 4 + c];
        for (int c = 0; c < 4; ++c) M[r][4 + c] = (r == c) ? 1.f : 0.f;
    }
    for (int col = 0; col < 4; ++col) {
        int piv = col;
        float best = fabsf(M[col][col]);
        for (int r = col + 1; r < 4; ++r) {
            float v = fabsf(M[r][col]);
            if (v > best) { best = v; piv = r; }
        }
        if (piv != col)
            for (int c = 0; c < 8; ++c) {
                float t = M[col][c]; M[col][c] = M[piv][c]; M[piv][c] = t;
            }
        float d = 1.f / M[col][col];
        for (int c = 0; c < 8; ++c) M[col][c] *= d;
        for (int r = 0; r < 4; ++r) {
            if (r == col) continue;
            float f = M[r][col];
            for (int c = 0; c < 8; ++c) M[r][c] -= f * M[col][c];
        }
    }
    for (int r = 0; r < 4; ++r)
        for (int c = 0; c < 4; ++c) inv[r * 4 + c] = M[r][4 + c];
}

__global__ void compute_T_kernel(const float* __restrict__ rot,
                                 const float* __restrict__ trans,
                                 const float* __restrict__ ref_v2r,
                                 const float* __restrict__ flo_v2r,
                                 float* __restrict__ T_out) {
    if (threadIdx.x != 0 || blockIdx.x != 0) return;

    float cx = cosf(rot[0]), cy = cosf(rot[1]), cz = cosf(rot[2]);
    float sx = sinf(rot[0]), sy = sinf(rot[1]), sz = sinf(rot[2]);

    // Ry @ Rz
    float Ryz[3][3] = {
        { cy * cz, -cy * sz,  sy },
        { sz,       cz,       0.f },
        { -sy * cz, sy * sz,  cy }
    };
    // R = Rx @ (Ry @ Rz);  Rx = [[1,0,0],[0,cx,-sx],[0,sx,cx]]
    float R[3][3];
    for (int c = 0; c < 3; ++c) {
        R[0][c] = Ryz[0][c];
        R[1][c] = cx * Ryz[1][c] - sx * Ryz[2][c];
        R[2][c] = sx * Ryz[1][c] + cx * Ryz[2][c];
    }

    float Trig[16] = { R[0][0], R[0][1], R[0][2], trans[0],
                       R[1][0], R[1][1], R[1][2], trans[1],
                       R[2][0], R[2][1], R[2][2], trans[2],
                       0.f, 0.f, 0.f, 1.f };

    float ref[16], flo[16];
    for (int i = 0; i < 16; ++i) { ref[i] = ref_v2r[i]; flo[i] = flo_v2r[i]; }

    float inv_flo[16];
    invert4(flo, inv_flo);

    float M1[16];           // T_rig @ ref_v2r
    matmul4(Trig, ref, M1);
    float T[16];            // inv(flo) @ (T_rig @ ref_v2r)
    matmul4(inv_flo, M1, T);

    for (int i = 0; i < 12; ++i) T_out[i] = T[i];
}

// ---------------------------------------------------------------------------
// Warp kernel = R8 (z-pair gathers, 91 us) + explicit 4-row issue/consume
// pipeline and a raised VGPR budget.
//
//   - k = threadIdx.x (stride-1 lanes).  R5 lesson: never break this.
//   - XCD-slab sweep (block b -> XCD b&7): FETCH 470 -> 33 MB (R3).
//   - z-pair dwordx2 gathers (R8: 113 -> 91 us).
//   - R6/R7/R8 lesson: at VGPR=32 the compiler serializes load batches
//     (only ~7 loads in flight/CU, 53 cyc/load).  Fix: launch_bounds
//     min-waves 4/EU (16 waves/CU cap, >= measured 55% occupancy) frees
//     up to 128 VGPR, and the trip is split into phase 1 (16 loads
//     issued, results + weights held in statically-indexed reg arrays)
//     / phase 2 (selects + FMA + stores) -> 4x loads in flight/wave.
// ---------------------------------------------------------------------------

__global__ __launch_bounds__(256, 4)
void warp_trilinear_kernel(const float* __restrict__ X,
                           const float* __restrict__ Tm,
                           float* __restrict__ out) {
    __shared__ float T[12];
    if (threadIdx.x < 12) T[threadIdx.x] = Tm[threadIdx.x];
    __syncthreads();

    const float t00 = T[0], t01 = T[1], t02 = T[2], t03 = T[3];
    const float t10 = T[4], t11 = T[5], t12 = T[6], t13 = T[7];
    const float t20 = T[8], t21 = T[9], t22 = T[10], t23 = T[11];

    const int xcd = blockIdx.x & 7;       // assumed XCD id (round-robin)
    const int l   = blockIdx.x >> 3;      // 0..255: j-lane within the plane
    const int k   = threadIdx.x;          // 0..255: k coordinate (stride-1!)
    const float fk = (float)k;

    const int i0  = xcd << 5;             // first i-plane of this XCD's slab
    const int j   = l;
    const float fj = (float)j;

    #pragma unroll 1
    for (int iter = 0; iter < 32; iter += 4) {
        // per-row state, statically indexed (stays in VGPRs)
        f2v   pff[4], pfc[4], pcf[4], pcc[4];
        float wff[4], wfc[4], wcf[4], wcc[4], wfz_[4], wcz_[4];
        bool  okv[4], zhi[4];

        // ---- phase 1: coords, weights, issue all 16 loads ----
        #pragma unroll
        for (int u = 0; u < 4; ++u) {
            const int i = i0 + iter + u;
            const float fi = (float)i;

            const float di = t00 * fi + t01 * fj + t02 * fk + t03;
            const float dj = t10 * fi + t11 * fj + t12 * fk + t13;
            const float dk = t20 * fi + t21 * fj + t22 * fk + t23;

            okv[u] = (di > 0.f) & (dj > 0.f) & (dk > 0.f) &
                     (di <= 255.f) & (dj <= 255.f) & (dk <= 255.f);

            const float fx = floorf(di), fy = floorf(dj), fz = floorf(dk);
            const float wcx = di - fx, wcy = dj - fy, wcz = dk - fz;
            const float wfx = 1.f - wcx, wfy = 1.f - wcy, wfz = 1.f - wcz;

            wff[u] = wfx * wfy;  wfc[u] = wfx * wcy;
            wcf[u] = wcx * wfy;  wcc[u] = wcx * wcy;
            wfz_[u] = wfz;       wcz_[u] = wcz;

            const int fxi = min(max((int)fx, 0), DIM - 1);
            const int fyi = min(max((int)fy, 0), DIM - 1);
            const int fzi = min(max((int)fz, 0), DIM - 1);
            const int cxi = min(max((int)fx + 1, 0), DIM - 1);
            const int cyi = min(max((int)fy + 1, 0), DIM - 1);

            const int bff = (fxi << 16) + (fyi << 8);
            const int bfc = (fxi << 16) + (cyi << 8);
            const int bcf = (cxi << 16) + (fyi << 8);
            const int bcc = (cxi << 16) + (cyi << 8);

            const int zb = min(fzi, DIM - 2);     // [0,254]: pair in-bounds
            zhi[u] = (fzi == DIM - 1);            // only when dk==255 (w=0)

            pff[u] = *(const f2v*)(X + bff + zb);
            pfc[u] = *(const f2v*)(X + bfc + zb);
            pcf[u] = *(const f2v*)(X + bcf + zb);
            pcc[u] = *(const f2v*)(X + bcc + zb);
        }

        // ---- phase 2: selects, weighted sums, stores ----
        #pragma unroll
        for (int u = 0; u < 4; ++u) {
            const float v000 = zhi[u] ? pff[u].y : pff[u].x;
            const float v001 = pff[u].y;
            const float v010 = zhi[u] ? pfc[u].y : pfc[u].x;
            const float v011 = pfc[u].y;
            const float v100 = zhi[u] ? pcf[u].y : pcf[u].x;
            const float v101 = pcf[u].y;
            const float v110 = zhi[u] ? pcc[u].y : pcc[u].x;
            const float v111 = pcc[u].y;

            float val = v000 * (wff[u] * wfz_[u]) + v001 * (wff[u] * wcz_[u]) +
                        v010 * (wfc[u] * wfz_[u]) + v011 * (wfc[u] * wcz_[u]) +
                        v100 * (wcf[u] * wfz_[u]) + v101 * (wcf[u] * wcz_[u]) +
                        v110 * (wcc[u] * wfz_[u]) + v111 * (wcc[u] * wcz_[u]);

            const int row = ((i0 + iter + u) << 8) + j;      // i*256 + j
            out[(row << 8) + k] = okv[u] ? val : 0.f;
        }
    }
}

extern "C" void kernel_launch(void* const* d_in, const int* in_sizes, int n_in,
                              void* d_out, int out_size, void* d_ws, size_t ws_size,
                              hipStream_t stream) {
    const float* image   = (const float*)d_in[0];  // [1,1,256,256,256]
    const float* rot     = (const float*)d_in[1];  // [1,3]
    const float* trans   = (const float*)d_in[2];  // [1,3]
    const float* ref_v2r = (const float*)d_in[3];  // [4,4]
    const float* flo_v2r = (const float*)d_in[4];  // [4,4]
    float* out = (float*)d_out;
    float* Tws = (float*)d_ws;                     // 12 floats

    compute_T_kernel<<<1, 64, 0, stream>>>(rot, trans, ref_v2r, flo_v2r, Tws);

    // 2048 blocks x 256 threads; each block does 32 rows (4 per trip).
    warp_trilinear_kernel<<<2048, 256, 0, stream>>>(image, Tws, out);
}